// Round 7
// baseline (101.011 us; speedup 1.0000x reference)
//
#include <hip/hip_runtime.h>

// DeformableConv2D round 11: r10 + software-pipelined HALF-TAP phase B.
//
// r10 post-mortem: direct A-frag build from the LDS window dropped main to
// ~39us (bench 94.6; the 40us harness fillBuffer now dominates the top-5).
// Remaining phase-B structure is serial per tap: 16 ds_read_b128 -> lgkm wait
// (~120cy) -> 64 FMA + 16 cvt -> 2 MFMA; next tap's reads wait for the blend.
// At 3 waves/SIMD that latency is only partly hidden.
//
// This round (numerics IDENTICAL to r10 -- same f32 blend, same tables):
// phase B pipelined at half-tap granularity. Half-stage = 8 corner reads
// (32 VGPR buffer) -> blend -> 1 MFMA. Two buffers double-buffer the stages:
// stage n+1's reads are issued BEFORE stage n's blend, so the ~120cy LDS
// latency hides under ~80cy of blend VALU + MFMA. VGPR headroom is free:
// (256,3) caps at ~168, r10 used 68; LDS (52.4KB -> 3 blocks/CU) is the
// occupancy limit either way.
//
// LDS: s_win 23040 + s_winh 11520 + s_off 4032 + s_cww 9216 + s_cwl 4608
//    = 52416 B -> 3 blocks/CU. Barriers per block: 3.
//
// MFMA 16x16x32 f16 layouts (verified by earlier passing runs):
//   A-frag: lane holds A[m=lane&15][k=(lane>>4)*8+j]
//   B-frag: lane holds B[k=(lane>>4)*8+j][n=lane&15]   (B stored [n][k])
//   C/D  : col(n)=lane&15, row(m)=(lane>>4)*4+reg

#define NH 56
#define NW 56
#define NC 64
#define NDG 4
#define NK 9
#define NOFF 72
#define NOFFP 80
#define NF 64
#define KTOT 576
#define HWPIX 3136
#define NPIX 12544

#define PW    14            // pixels per block (one row segment; 4 segs/row)
#define WR    5             // window rows  (oh-2 .. oh+2)
#define WC    18            // window cols  (ow0-2 .. ow0+15)
#define WPOS  (WR * WC)     // 90 positions
#define NBLK  (4 * NH * 4)  // 896

#define WS_OFFKT 0          // f16 [80][576]   = 92160 B
#define WS_WK    92160      // f16 [9][64][64] = 73728 B

typedef _Float16 half8   __attribute__((ext_vector_type(8)));
typedef _Float16 half4   __attribute__((ext_vector_type(4)));
typedef float    floatx4 __attribute__((ext_vector_type(4)));

// ---------------- prep: weight conversion ----------------
__global__ __launch_bounds__(256)
void dcn_prep(const float* __restrict__ offk,   // [3,3,64,72] (kk,oc)
              const float* __restrict__ wk,     // [3,3,64,64] (k,f,c)
              _Float16* __restrict__ offkt,     // [80][576]   (oc,kk)
              _Float16* __restrict__ wkh)       // [9][64][64]
{
    const int i = blockIdx.x * 256 + threadIdx.x;
    if (i < NOFFP * KTOT) {
        const int oc = i / KTOT;
        const int kk = i - oc * KTOT;
        const float v = (oc < NOFF) ? offk[kk * NOFF + oc] : 0.0f;
        offkt[i] = (_Float16)v;
    }
    const int j = i - NOFFP * KTOT;
    if (j >= 0 && j < NK * NF * NC) wkh[j] = (_Float16)wk[j];
}

// window swizzles (keep 16B granules contiguous; spread banks across pos)
__device__ __forceinline__ int win_idx(int pos, int c) {      // f32, dword units
    return (pos << 6) + (c ^ ((pos & 7) << 2));
}
__device__ __forceinline__ int winh_idx(int pos, int c) {     // f16, elem units
    return (pos << 6) + (c ^ ((pos & 7) << 3));
}

// ---------------- fused main ----------------
__global__ __launch_bounds__(256, 3)
void dcn_main(const float* __restrict__ x,        // [4,56,56,64]
              const _Float16* __restrict__ offkt, // [80][576]
              const float* __restrict__ offb,     // [72]
              const _Float16* __restrict__ wkh,   // [9][64][64]
              float* __restrict__ out)            // [12544][64]
{
    __shared__ __align__(16) float    s_win[WPOS * NC];     // 23040 B
    __shared__ __align__(16) _Float16 s_winh[WPOS * NC];    // 11520 B
    __shared__ float s_off[PW * NOFF];                      // 4032 B
    __shared__ __align__(16) float s_cww[36 * 16 * 4];      // 9216 B  [k*4+w][p]
    __shared__ __align__(8)  unsigned s_cwl[36 * 16 * 2];   // 4608 B  [k*4+w][p]

    const int tid  = threadIdx.x;
    const int w    = tid >> 6;      // wave id: A = N-tile, B = group
    const int lane = tid & 63;
    const int m    = lane & 15;     // MFMA row / col index
    const int kq   = lane >> 4;     // MFMA k-quad
    const int kq8  = kq * 8;

    // block -> (b, oh, ow0)
    const int blk = blockIdx.x;
    const int b   = blk / (NH * 4);
    const int r2  = blk - b * (NH * 4);
    const int oh  = r2 >> 2;
    const int ow0 = (r2 & 3) * PW;
    const int bb  = b * HWPIX;

    // ---- stage window (f32 + f16 copies), zero-padded outside image ----
    for (int i = tid; i < WPOS * 16; i += 256) {
        const int pos = i >> 4;
        const int g4  = (i & 15) * 4;
        const int ry  = pos / WC;
        const int rx  = pos - ry * WC;
        const int iy  = oh + ry - 2;
        const int ix  = ow0 + rx - 2;
        float4 v = make_float4(0.f, 0.f, 0.f, 0.f);
        if ((unsigned)iy < NH && (unsigned)ix < NW)
            v = *(const float4*)&x[(size_t)((bb + iy * NW + ix) * NC) + g4];
        *(float4*)&s_win[win_idx(pos, g4)] = v;
        half4 h;
        h[0] = (_Float16)v.x; h[1] = (_Float16)v.y;
        h[2] = (_Float16)v.z; h[3] = (_Float16)v.w;
        *(half4*)&s_winh[winh_idx(pos, g4)] = h;
    }
    __syncthreads();

    // ---- phase A: offset conv GEMM from f16 window, zero cvt chains ----
    const int oc0 = w * 16 + m;     // 0..63
    floatx4 acc0, acc1;
    { const float bv = offb[oc0]; acc0 = (floatx4){bv, bv, bv, bv}; }
    { const float bv = (w == 3 && m < 8) ? offb[64 + m] : 0.0f;
      acc1 = (floatx4){bv, bv, bv, bv}; }

    #pragma unroll
    for (int k = 0; k < NK; ++k) {
        const int ki = k / 3, kj = k - 3 * ki;
        const int pos = (ki + 1) * WC + (m + kj + 1);   // m>=PW: garbage, masked
        #pragma unroll
        for (int s = 0; s < 2; ++s) {
            const half8 af = *(const half8*)&s_winh[winh_idx(pos, s * 32 + kq8)];
            const int kkb = k * 64 + s * 32 + kq8;
            const half8 bf0 = *(const half8*)&offkt[(size_t)oc0 * KTOT + kkb];
            acc0 = __builtin_amdgcn_mfma_f32_16x16x32_f16(af, bf0, acc0, 0, 0, 0);
            if (w == 3) {
                const half8 bf1 = *(const half8*)&offkt[(size_t)(64 + m) * KTOT + kkb];
                acc1 = __builtin_amdgcn_mfma_f32_16x16x32_f16(af, bf1, acc1, 0, 0, 0);
            }
        }
    }
    #pragma unroll
    for (int r = 0; r < 4; ++r)
        if (kq * 4 + r < PW)
            s_off[(kq * 4 + r) * NOFF + oc0] = acc0[r];
    if (w == 3 && m < 8) {
        #pragma unroll
        for (int r = 0; r < 4; ++r)
            if (kq * 4 + r < PW)
                s_off[(kq * 4 + r) * NOFF + 64 + m] = acc1[r];
    }
    __syncthreads();

    // ---- phase A': coord/weight table, slot = (k*4+g)*16 + p ----
    for (int i = tid; i < 36 * 16; i += 256) {
        const int kg = i >> 4;                  // k*NDG + g
        const int p  = i & 15;
        float4 wv = make_float4(0.f, 0.f, 0.f, 0.f);
        unsigned c0 = 0, c1 = 0;                // pad slots: pos 0, weight 0
        if (p < PW) {
            const int k  = kg >> 2;
            const int ki = k / 3, kj = k - 3 * ki;
            const int ow = ow0 + p;
            const float offy = s_off[p * NOFF + kg * 2 + 0];
            const float offx = s_off[p * NOFF + kg * 2 + 1];
            float yv = fminf(fmaxf((float)(oh + ki) + offy, 0.0f), 57.0f);
            float xv = fminf(fmaxf((float)(ow + kj) + offx, 0.0f), 57.0f);
            const float y0f = floorf(yv), x0f = floorf(xv);
            const int y0 = (int)y0f, x0 = (int)x0f;
            const int y1 = min(y0 + 1, 57), x1 = min(x0 + 1, 57);
            const float ly = yv - y0f,       lx = xv - x0f;
            const float hy = (float)y1 - yv, hx = (float)x1 - xv;
            const bool vy0 = (unsigned)(y0 - 1) < NH;
            const bool vy1 = (unsigned)(y1 - 1) < NH;
            const bool vx0 = (unsigned)(x0 - 1) < NW;
            const bool vx1 = (unsigned)(x1 - 1) < NW;
            wv = make_float4((vy0 && vx0) ? hy * hx : 0.0f,
                             (vy0 && vx1) ? hy * lx : 0.0f,
                             (vy1 && vx0) ? ly * hx : 0.0f,
                             (vy1 && vx1) ? ly * lx : 0.0f);
            const int y0c = min(max(y0 - 1, 0), NH - 1);
            const int y1c = min(max(y1 - 1, 0), NH - 1);
            const int x0c = min(max(x0 - 1, 0), NW - 1);
            const int x1c = min(max(x1 - 1, 0), NW - 1);
            const int ry0 = y0c - oh + 2, ry1 = y1c - oh + 2;
            const int rx0 = x0c - ow0 + 2, rx1 = x1c - ow0 + 2;
            if ((unsigned)ry0 < WR && (unsigned)ry1 < WR &&
                (unsigned)rx0 < WC && (unsigned)rx1 < WC) {
                c0 = (unsigned)(ry0 * WC + rx0) | ((unsigned)(ry0 * WC + rx1) << 16);
                c1 = (unsigned)(ry1 * WC + rx0) | ((unsigned)(ry1 * WC + rx1) << 16);
            } else {                            // rare: packed clamped coords
                c0 = 0x80000000u | ((unsigned)y0c << 18) | ((unsigned)x0c << 12)
                   | ((unsigned)y1c << 6) | (unsigned)x1c;
                c1 = c0;
            }
        }
        *(float4*)&s_cww[i * 4] = wv;
        s_cwl[i * 2 + 0] = c0;
        s_cwl[i * 2 + 1] = c1;
    }
    __syncthreads();

    // ---- phase B: half-tap software pipeline, zero LDS writes ----
    floatx4 accB = (floatx4){0.f, 0.f, 0.f, 0.f};
    const int tb = w * 16 + m;                  // table slot (pixel m, group w)

    floatx4 bufA[8], bufB[8];                   // two half-stage corner buffers

    auto read_half = [&](int kk, int cofs, floatx4* buf) {
        const int sl = kk * 64 + tb;
        const unsigned cc0 = s_cwl[sl * 2 + 0];
        const unsigned cc1 = s_cwl[sl * 2 + 1];
        if (__builtin_expect((cc0 & 0x80000000u) == 0, 1)) {
            const int p00 = cc0 & 0xFFFF, p01 = cc0 >> 16;
            const int p10 = cc1 & 0xFFFF, p11 = cc1 >> 16;
            buf[0] = *(const floatx4*)&s_win[win_idx(p00, cofs)];
            buf[1] = *(const floatx4*)&s_win[win_idx(p00, cofs + 4)];
            buf[2] = *(const floatx4*)&s_win[win_idx(p01, cofs)];
            buf[3] = *(const floatx4*)&s_win[win_idx(p01, cofs + 4)];
            buf[4] = *(const floatx4*)&s_win[win_idx(p10, cofs)];
            buf[5] = *(const floatx4*)&s_win[win_idx(p10, cofs + 4)];
            buf[6] = *(const floatx4*)&s_win[win_idx(p11, cofs)];
            buf[7] = *(const floatx4*)&s_win[win_idx(p11, cofs + 4)];
        } else {
            const int y0c = (cc0 >> 18) & 63, x0c = (cc0 >> 12) & 63;
            const int y1c = (cc0 >> 6) & 63,  x1c = cc0 & 63;
            const int i00 = (bb + y0c * NW + x0c) * NC + cofs;
            const int i01 = (bb + y0c * NW + x1c) * NC + cofs;
            const int i10 = (bb + y1c * NW + x0c) * NC + cofs;
            const int i11 = (bb + y1c * NW + x1c) * NC + cofs;
            buf[0] = *(const floatx4*)&x[i00];
            buf[1] = *(const floatx4*)&x[i00 + 4];
            buf[2] = *(const floatx4*)&x[i01];
            buf[3] = *(const floatx4*)&x[i01 + 4];
            buf[4] = *(const floatx4*)&x[i10];
            buf[5] = *(const floatx4*)&x[i10 + 4];
            buf[6] = *(const floatx4*)&x[i11];
            buf[7] = *(const floatx4*)&x[i11 + 4];
        }
    };

    auto blend_half = [&](float4 cwv, const floatx4* buf) -> half8 {
        half8 af;
        #pragma unroll
        for (int j = 0; j < 4; ++j) {
            float v0 = cwv.x * buf[0][j];
            v0 = fmaf(cwv.y, buf[2][j], v0);
            v0 = fmaf(cwv.z, buf[4][j], v0);
            v0 = fmaf(cwv.w, buf[6][j], v0);
            af[j] = (_Float16)v0;
            float v1 = cwv.x * buf[1][j];
            v1 = fmaf(cwv.y, buf[3][j], v1);
            v1 = fmaf(cwv.z, buf[5][j], v1);
            v1 = fmaf(cwv.w, buf[7][j], v1);
            af[4 + j] = (_Float16)v1;
        }
        return af;
    };

    read_half(0, kq8, bufA);                    // prologue: tap0 lo-half
    float4 cw = *(const float4*)&s_cww[tb * 4];

    #pragma unroll 1
    for (int k = 0; k < NK; ++k) {
        const _Float16* wp = &wkh[(size_t)(k * NF + w * 16 + m) * NC];
        const half8 bf0 = *(const half8*)&wp[kq8];
        const half8 bf1 = *(const half8*)&wp[32 + kq8];

        read_half(k, 32 + kq8, bufB);           // issue hi-half of tap k
        const half8 af0 = blend_half(cw, bufA); // consume lo-half of tap k
        accB = __builtin_amdgcn_mfma_f32_16x16x32_f16(af0, bf0, accB, 0, 0, 0);

        float4 cwn = cw;
        if (k + 1 < NK) {
            read_half(k + 1, kq8, bufA);        // issue lo-half of tap k+1
            cwn = *(const float4*)&s_cww[((k + 1) * 64 + tb) * 4];
        }
        const half8 af1 = blend_half(cw, bufB); // consume hi-half of tap k
        accB = __builtin_amdgcn_mfma_f32_16x16x32_f16(af1, bf1, accB, 0, 0, 0);
        cw = cwn;
    }

    #pragma unroll
    for (int r = 0; r < 4; ++r) {
        const int row = kq * 4 + r;
        if (row < PW)
            out[(size_t)(bb + oh * NW + ow0 + row) * NF + w * 16 + m] = accB[r];
    }
}

extern "C" void kernel_launch(void* const* d_in, const int* in_sizes, int n_in,
                              void* d_out, int out_size, void* d_ws, size_t ws_size,
                              hipStream_t stream) {
    const float* xin  = (const float*)d_in[0];
    const float* offk = (const float*)d_in[1];
    const float* offb = (const float*)d_in[2];
    const float* wk   = (const float*)d_in[3];
    float* outp = (float*)d_out;

    _Float16* offkt = (_Float16*)((char*)d_ws + WS_OFFKT);
    _Float16* wkh   = (_Float16*)((char*)d_ws + WS_WK);

    dcn_prep<<<324, 256, 0, stream>>>(offk, wk, offkt, wkh);
    dcn_main<<<NBLK, 256, 0, stream>>>(xin, offkt, offb, wkh, outp);
}

// Round 8
// 86.682 us; speedup vs baseline: 1.1653x; 1.1653x over previous
//
#include <hip/hip_runtime.h>

// DeformableConv2D round 12: r10 structure, f16-only window (s_win deleted).
//
// r11 post-mortem: half-tap pipeline regressed (VGPR stayed 68 -- compiler
// never kept 2 buffers live past the divergent fallback; s_cwl traffic
// doubled). But it exposed main's counters: SQ_LDS_BANK_CONFLICT 7.3M, ~14
// extra cy per phase-B ds_read_b128 => corner reads are the dominant LDS cost
// (~12us of pipe serialization). r10 shares that read pattern.
//
// This round: MFMA eats f16 anyway, and v_fma_mix_f32 blends f16 sources with
// f32 accumulation. So drop the f32 window copy entirely:
//   * phase-B corner reads come from s_winh: 8 ds_read_b128/tap (was 16)
//     -> LDS traffic and conflicts halve.
//   * staging writes halve (f16 only).
//   * LDS 52.4 -> 29.4 KB: 5 blocks/CU capacity, full grid residency
//     (896 blocks = 3.5/CU) now fits.
// Numerics: corners pre-rounded to f16 before the f32-accumulated blend
// (fallback path rounds too, for consistency). Phase-B code shape is r10's
// (which scheduled well) -- only the read source and blend inputs change.
//
// LDS: s_winh 11520 + s_off 4032 + s_cww 9216 + s_cwl 4608 = 29376 B.
// Barriers per block: 3.
//
// MFMA 16x16x32 f16 layouts (verified by earlier passing runs):
//   A-frag: lane holds A[m=lane&15][k=(lane>>4)*8+j]
//   B-frag: lane holds B[k=(lane>>4)*8+j][n=lane&15]   (B stored [n][k])
//   C/D  : col(n)=lane&15, row(m)=(lane>>4)*4+reg

#define NH 56
#define NW 56
#define NC 64
#define NDG 4
#define NK 9
#define NOFF 72
#define NOFFP 80
#define NF 64
#define KTOT 576
#define HWPIX 3136
#define NPIX 12544

#define PW    14            // pixels per block (one row segment; 4 segs/row)
#define WR    5             // window rows  (oh-2 .. oh+2)
#define WC    18            // window cols  (ow0-2 .. ow0+15)
#define WPOS  (WR * WC)     // 90 positions
#define NBLK  (4 * NH * 4)  // 896

#define WS_OFFKT 0          // f16 [80][576]   = 92160 B
#define WS_WK    92160      // f16 [9][64][64] = 73728 B

typedef _Float16 half8   __attribute__((ext_vector_type(8)));
typedef _Float16 half4   __attribute__((ext_vector_type(4)));
typedef float    floatx4 __attribute__((ext_vector_type(4)));

// ---------------- prep: weight conversion ----------------
__global__ __launch_bounds__(256)
void dcn_prep(const float* __restrict__ offk,   // [3,3,64,72] (kk,oc)
              const float* __restrict__ wk,     // [3,3,64,64] (k,f,c)
              _Float16* __restrict__ offkt,     // [80][576]   (oc,kk)
              _Float16* __restrict__ wkh)       // [9][64][64]
{
    const int i = blockIdx.x * 256 + threadIdx.x;
    if (i < NOFFP * KTOT) {
        const int oc = i / KTOT;
        const int kk = i - oc * KTOT;
        const float v = (oc < NOFF) ? offk[kk * NOFF + oc] : 0.0f;
        offkt[i] = (_Float16)v;
    }
    const int j = i - NOFFP * KTOT;
    if (j >= 0 && j < NK * NF * NC) wkh[j] = (_Float16)wk[j];
}

// f16 window swizzle (16B granules contiguous; spread banks across pos)
__device__ __forceinline__ int winh_idx(int pos, int c) {     // elem units
    return (pos << 6) + (c ^ ((pos & 7) << 3));
}

// ---------------- fused main ----------------
__global__ __launch_bounds__(256, 4)
void dcn_main(const float* __restrict__ x,        // [4,56,56,64]
              const _Float16* __restrict__ offkt, // [80][576]
              const float* __restrict__ offb,     // [72]
              const _Float16* __restrict__ wkh,   // [9][64][64]
              float* __restrict__ out)            // [12544][64]
{
    __shared__ __align__(16) _Float16 s_winh[WPOS * NC];    // 11520 B
    __shared__ float s_off[PW * NOFF];                      // 4032 B
    __shared__ __align__(16) float s_cww[36 * 16 * 4];      // 9216 B  [k*4+w][p]
    __shared__ __align__(8)  unsigned s_cwl[36 * 16 * 2];   // 4608 B  [k*4+w][p]

    const int tid  = threadIdx.x;
    const int w    = tid >> 6;      // wave id: A = N-tile, B = group
    const int lane = tid & 63;
    const int m    = lane & 15;     // MFMA row / col index
    const int kq   = lane >> 4;     // MFMA k-quad
    const int kq8  = kq * 8;

    // block -> (b, oh, ow0)
    const int blk = blockIdx.x;
    const int b   = blk / (NH * 4);
    const int r2  = blk - b * (NH * 4);
    const int oh  = r2 >> 2;
    const int ow0 = (r2 & 3) * PW;
    const int bb  = b * HWPIX;

    // ---- stage window (f16), zero-padded outside image ----
    for (int i = tid; i < WPOS * 16; i += 256) {
        const int pos = i >> 4;
        const int g4  = (i & 15) * 4;
        const int ry  = pos / WC;
        const int rx  = pos - ry * WC;
        const int iy  = oh + ry - 2;
        const int ix  = ow0 + rx - 2;
        float4 v = make_float4(0.f, 0.f, 0.f, 0.f);
        if ((unsigned)iy < NH && (unsigned)ix < NW)
            v = *(const float4*)&x[(size_t)((bb + iy * NW + ix) * NC) + g4];
        half4 h;
        h[0] = (_Float16)v.x; h[1] = (_Float16)v.y;
        h[2] = (_Float16)v.z; h[3] = (_Float16)v.w;
        *(half4*)&s_winh[winh_idx(pos, g4)] = h;
    }
    __syncthreads();

    // ---- phase A: offset conv GEMM from f16 window ----
    const int oc0 = w * 16 + m;     // 0..63
    floatx4 acc0, acc1;
    { const float bv = offb[oc0]; acc0 = (floatx4){bv, bv, bv, bv}; }
    { const float bv = (w == 3 && m < 8) ? offb[64 + m] : 0.0f;
      acc1 = (floatx4){bv, bv, bv, bv}; }

    #pragma unroll
    for (int k = 0; k < NK; ++k) {
        const int ki = k / 3, kj = k - 3 * ki;
        const int pos = (ki + 1) * WC + (m + kj + 1);   // m>=PW: garbage, masked
        #pragma unroll
        for (int s = 0; s < 2; ++s) {
            const half8 af = *(const half8*)&s_winh[winh_idx(pos, s * 32 + kq8)];
            const int kkb = k * 64 + s * 32 + kq8;
            const half8 bf0 = *(const half8*)&offkt[(size_t)oc0 * KTOT + kkb];
            acc0 = __builtin_amdgcn_mfma_f32_16x16x32_f16(af, bf0, acc0, 0, 0, 0);
            if (w == 3) {
                const half8 bf1 = *(const half8*)&offkt[(size_t)(64 + m) * KTOT + kkb];
                acc1 = __builtin_amdgcn_mfma_f32_16x16x32_f16(af, bf1, acc1, 0, 0, 0);
            }
        }
    }
    #pragma unroll
    for (int r = 0; r < 4; ++r)
        if (kq * 4 + r < PW)
            s_off[(kq * 4 + r) * NOFF + oc0] = acc0[r];
    if (w == 3 && m < 8) {
        #pragma unroll
        for (int r = 0; r < 4; ++r)
            if (kq * 4 + r < PW)
                s_off[(kq * 4 + r) * NOFF + 64 + m] = acc1[r];
    }
    __syncthreads();

    // ---- phase A': coord/weight table, slot = (k*4+g)*16 + p ----
    for (int i = tid; i < 36 * 16; i += 256) {
        const int kg = i >> 4;                  // k*NDG + g
        const int p  = i & 15;
        float4 wv = make_float4(0.f, 0.f, 0.f, 0.f);
        unsigned c0 = 0, c1 = 0;                // pad slots: pos 0, weight 0
        if (p < PW) {
            const int k  = kg >> 2;
            const int ki = k / 3, kj = k - 3 * ki;
            const int ow = ow0 + p;
            const float offy = s_off[p * NOFF + kg * 2 + 0];
            const float offx = s_off[p * NOFF + kg * 2 + 1];
            float yv = fminf(fmaxf((float)(oh + ki) + offy, 0.0f), 57.0f);
            float xv = fminf(fmaxf((float)(ow + kj) + offx, 0.0f), 57.0f);
            const float y0f = floorf(yv), x0f = floorf(xv);
            const int y0 = (int)y0f, x0 = (int)x0f;
            const int y1 = min(y0 + 1, 57), x1 = min(x0 + 1, 57);
            const float ly = yv - y0f,       lx = xv - x0f;
            const float hy = (float)y1 - yv, hx = (float)x1 - xv;
            const bool vy0 = (unsigned)(y0 - 1) < NH;
            const bool vy1 = (unsigned)(y1 - 1) < NH;
            const bool vx0 = (unsigned)(x0 - 1) < NW;
            const bool vx1 = (unsigned)(x1 - 1) < NW;
            wv = make_float4((vy0 && vx0) ? hy * hx : 0.0f,
                             (vy0 && vx1) ? hy * lx : 0.0f,
                             (vy1 && vx0) ? ly * hx : 0.0f,
                             (vy1 && vx1) ? ly * lx : 0.0f);
            const int y0c = min(max(y0 - 1, 0), NH - 1);
            const int y1c = min(max(y1 - 1, 0), NH - 1);
            const int x0c = min(max(x0 - 1, 0), NW - 1);
            const int x1c = min(max(x1 - 1, 0), NW - 1);
            const int ry0 = y0c - oh + 2, ry1 = y1c - oh + 2;
            const int rx0 = x0c - ow0 + 2, rx1 = x1c - ow0 + 2;
            if ((unsigned)ry0 < WR && (unsigned)ry1 < WR &&
                (unsigned)rx0 < WC && (unsigned)rx1 < WC) {
                c0 = (unsigned)(ry0 * WC + rx0) | ((unsigned)(ry0 * WC + rx1) << 16);
                c1 = (unsigned)(ry1 * WC + rx0) | ((unsigned)(ry1 * WC + rx1) << 16);
            } else {                            // rare: packed clamped coords
                c0 = 0x80000000u | ((unsigned)y0c << 18) | ((unsigned)x0c << 12)
                   | ((unsigned)y1c << 6) | (unsigned)x1c;
                c1 = c0;
            }
        }
        *(float4*)&s_cww[i * 4] = wv;
        s_cwl[i * 2 + 0] = c0;
        s_cwl[i * 2 + 1] = c1;
    }
    __syncthreads();

    // ---- phase B: direct f16 A-frag build from window, zero LDS writes ----
    floatx4 accB = (floatx4){0.f, 0.f, 0.f, 0.f};
    const int tb = w * 16 + m;                  // table slot (pixel m, group w)
    float4   cw = *(const float4*)&s_cww[tb * 4];
    unsigned c0 = s_cwl[tb * 2 + 0];
    unsigned c1 = s_cwl[tb * 2 + 1];
    #pragma unroll 1
    for (int k = 0; k < NK; ++k) {
        const int tn = (k + 1 < NK ? k + 1 : k) * 64 + tb;
        const float4   cwn = *(const float4*)&s_cww[tn * 4];
        const unsigned c0n = s_cwl[tn * 2 + 0];
        const unsigned c1n = s_cwl[tn * 2 + 1];

        const _Float16* wp = &wkh[(size_t)(k * NF + w * 16 + m) * NC];
        const half8 bf0 = *(const half8*)&wp[kq8];
        const half8 bf1 = *(const half8*)&wp[32 + kq8];

        half8 q00a, q01a, q10a, q11a;           // s=0 corners (8 f16 each)
        half8 q00b, q01b, q10b, q11b;           // s=1 corners
        if (__builtin_expect((c0 & 0x80000000u) == 0, 1)) {
            const int p00 = c0 & 0xFFFF, p01 = c0 >> 16;
            const int p10 = c1 & 0xFFFF, p11 = c1 >> 16;
            const int ca = kq8, cb = 32 + kq8;
            q00a = *(const half8*)&s_winh[winh_idx(p00, ca)];
            q01a = *(const half8*)&s_winh[winh_idx(p01, ca)];
            q10a = *(const half8*)&s_winh[winh_idx(p10, ca)];
            q11a = *(const half8*)&s_winh[winh_idx(p11, ca)];
            q00b = *(const half8*)&s_winh[winh_idx(p00, cb)];
            q01b = *(const half8*)&s_winh[winh_idx(p01, cb)];
            q10b = *(const half8*)&s_winh[winh_idx(p10, cb)];
            q11b = *(const half8*)&s_winh[winh_idx(p11, cb)];
        } else {
            const int y0c = (c0 >> 18) & 63, x0c = (c0 >> 12) & 63;
            const int y1c = (c0 >> 6) & 63,  x1c = c0 & 63;
            const int i00 = (bb + y0c * NW + x0c) * NC;
            const int i01 = (bb + y0c * NW + x1c) * NC;
            const int i10 = (bb + y1c * NW + x0c) * NC;
            const int i11 = (bb + y1c * NW + x1c) * NC;
            #pragma unroll
            for (int j = 0; j < 8; ++j) {
                q00a[j] = (_Float16)x[i00 + kq8 + j];
                q01a[j] = (_Float16)x[i01 + kq8 + j];
                q10a[j] = (_Float16)x[i10 + kq8 + j];
                q11a[j] = (_Float16)x[i11 + kq8 + j];
                q00b[j] = (_Float16)x[i00 + 32 + kq8 + j];
                q01b[j] = (_Float16)x[i01 + 32 + kq8 + j];
                q10b[j] = (_Float16)x[i10 + 32 + kq8 + j];
                q11b[j] = (_Float16)x[i11 + 32 + kq8 + j];
            }
        }

        half8 af0, af1;
        #pragma unroll
        for (int j = 0; j < 8; ++j) {
            float v0 = cw.x * (float)q00a[j];       // v_fma_mix_f32 chain
            v0 = fmaf(cw.y, (float)q01a[j], v0);
            v0 = fmaf(cw.z, (float)q10a[j], v0);
            v0 = fmaf(cw.w, (float)q11a[j], v0);
            af0[j] = (_Float16)v0;
            float v1 = cw.x * (float)q00b[j];
            v1 = fmaf(cw.y, (float)q01b[j], v1);
            v1 = fmaf(cw.z, (float)q10b[j], v1);
            v1 = fmaf(cw.w, (float)q11b[j], v1);
            af1[j] = (_Float16)v1;
        }
        accB = __builtin_amdgcn_mfma_f32_16x16x32_f16(af0, bf0, accB, 0, 0, 0);
        accB = __builtin_amdgcn_mfma_f32_16x16x32_f16(af1, bf1, accB, 0, 0, 0);
        cw = cwn; c0 = c0n; c1 = c1n;
    }

    #pragma unroll
    for (int r = 0; r < 4; ++r) {
        const int row = kq * 4 + r;
        if (row < PW)
            out[(size_t)(bb + oh * NW + ow0 + row) * NF + w * 16 + m] = accB[r];
    }
}

extern "C" void kernel_launch(void* const* d_in, const int* in_sizes, int n_in,
                              void* d_out, int out_size, void* d_ws, size_t ws_size,
                              hipStream_t stream) {
    const float* xin  = (const float*)d_in[0];
    const float* offk = (const float*)d_in[1];
    const float* offb = (const float*)d_in[2];
    const float* wk   = (const float*)d_in[3];
    float* outp = (float*)d_out;

    _Float16* offkt = (_Float16*)((char*)d_ws + WS_OFFKT);
    _Float16* wkh   = (_Float16*)((char*)d_ws + WS_WK);

    dcn_prep<<<324, 256, 0, stream>>>(offk, wk, offkt, wkh);
    dcn_main<<<NBLK, 256, 0, stream>>>(xin, offkt, offb, wkh, outp);
}